// Round 11
// baseline (794.150 us; speedup 1.0000x reference)
//
#include <hip/hip_runtime.h>
#include <math.h>

#define SS 2304
#define C_IN 256
#define HID 512
#define QKV3 1536
#define HEADS 8
#define DH 64
#define BATCH 4
#define EPSV 1e-5f
// SCALE folded with log2(e): softmax_j 2^(s_j*log2e) == softmax_j e^(s_j),
// so attention uses v_exp_f32 (2^x) directly with no per-p multiply.
#define SCALEV_LOG2E 0.18033688011112042f

typedef short s8v __attribute__((ext_vector_type(8)));
typedef float f4v __attribute__((ext_vector_type(4)));
typedef unsigned int u4v __attribute__((ext_vector_type(4)));
typedef unsigned int uint32;

static __device__ inline unsigned short f2bf(float x) {
    unsigned int u = __float_as_uint(x);
    u += 0x7fffu + ((u >> 16) & 1u);
    return (unsigned short)(u >> 16);
}
static __device__ inline float bf2f(unsigned short h) {
    return __uint_as_float((unsigned int)h << 16);
}
static __device__ inline f4v mm(s8v a, s8v b, f4v c) {
    return __builtin_amdgcn_mfma_f32_16x16x32_bf16(a, b, c, 0, 0, 0);
}
static __device__ inline s8v pk4(uint32 a, uint32 b, uint32 c, uint32 d) {
    u4v t; t[0] = a; t[1] = b; t[2] = c; t[3] = d;
    return __builtin_bit_cast(s8v, t);
}
// ---- hi/lo bf16 pack helpers (R19 v_perm final-assembly; operand-order safe:
// consumers symmetric under 16-bit rotation).  hi=rnd-nearest, lo=trunc residual.
static __device__ inline uint32 pk_rnd(float x) {
    unsigned int u = __float_as_uint(x);
    unsigned int uh = (u + (0x7fffu + ((u >> 16) & 1u))) & 0xffff0000u;
    float r = x - __uint_as_float(uh);
#if __has_builtin(__builtin_amdgcn_perm)
    return __builtin_amdgcn_perm(__float_as_uint(r), uh, 0x07060302u);
#else
    return (uh >> 16) | (__float_as_uint(r) & 0xffff0000u);
#endif
}
// trunc/trunc variant (cheap, hot attention path; softmax cancels the bias)
static __device__ inline uint32 pk_trunc(float x) {
    unsigned int u = __float_as_uint(x);
    unsigned int h = u & 0xffff0000u;
    float r = x - __uint_as_float(h);
#if __has_builtin(__builtin_amdgcn_perm)
    return __builtin_amdgcn_perm(__float_as_uint(r), u, 0x07060302u);
#else
    return (h >> 16) | (__float_as_uint(r) & 0xffff0000u);
#endif
}
// unpack {hi|lo} u32 back to ~fp32 (half-order agnostic: sums both halves)
static __device__ inline float unpk(uint32 u) {
    return __uint_as_float(u << 16) + __uint_as_float(u & 0xffff0000u);
}
static __device__ inline uint32 rot16(uint32 u) { return (u >> 16) | (u << 16); }
static __device__ inline u4v rot16v(u4v u) {
    u4v r; r[0] = rot16(u[0]); r[1] = rot16(u[1]); r[2] = rot16(u[2]); r[3] = rot16(u[3]);
    return r;
}

// ---- merged prep: [0,1536) wgint+wsum | [1536,2048) woutint | [2048,2336) rope ----
__global__ void prep_all(const float* __restrict__ w_qkv, const float* __restrict__ g,
                         uint32* __restrict__ wgint, float* __restrict__ wsum,
                         const float* __restrict__ w_out, uint32* __restrict__ woutint,
                         float* __restrict__ cosT, float* __restrict__ sinT) {
    __shared__ float red[256];
    int bid = blockIdx.x;
    int t = threadIdx.x;
    if (bid < QKV3) {
        int o = bid, c = t;
        float v = w_qkv[o * C_IN + c] * g[c];
        wgint[o * C_IN + c] = pk_rnd(v);
        red[c] = v;
        __syncthreads();
        for (int st = 128; st > 0; st >>= 1) {
            if (c < st) red[c] += red[c + st];
            __syncthreads();
        }
        if (c == 0) wsum[o] = red[0];
    } else if (bid < QKV3 + 512) {
        int idx = (bid - QKV3) * 256 + t;  // 131072 total
        woutint[idx] = pk_rnd(w_out[idx]);
    } else {
        int idx = (bid - QKV3 - 512) * 256 + t;  // 73728 total
        int s = idx >> 5, f = idx & 31;
        double inv = pow(10000.0, -(double)f / 32.0);
        double ang = (double)s * inv;
        cosT[idx] = (float)cos(ang);
        sinT[idx] = (float)sin(ang);
    }
}

// ------ transpose + pack x -> xTint[b][s][c] u32, and per-c-chunk LN partials ------
__global__ __launch_bounds__(256) void xt_pack(const float* __restrict__ x,
                                               uint32* __restrict__ xTint,
                                               float* __restrict__ psum,
                                               float* __restrict__ psq) {
    __shared__ float tile[64][65];
    __shared__ float sred[4][64];
    __shared__ float qred[4][64];
    int b = blockIdx.z;
    int c0 = blockIdx.y * 64;
    int s0 = blockIdx.x * 64;
    int t = threadIdx.x;
    int sl = t & 63, cg = t >> 6;
    float ps = 0.f, pq = 0.f;
#pragma unroll
    for (int i = 0; i < 16; ++i) {
        int c = cg * 16 + i;
        float v = x[((size_t)b * C_IN + c0 + c) * SS + s0 + sl];
        tile[c][sl] = v;
        ps += v;
        pq += v * v;
    }
    sred[cg][sl] = ps;
    qred[cg][sl] = pq;
    __syncthreads();
    int cl = t & 63, sg = t >> 6;
#pragma unroll
    for (int i = 0; i < 16; ++i) {
        int s = sg * 16 + i;
        xTint[((size_t)b * SS + s0 + s) * C_IN + c0 + cl] = pk_rnd(tile[cl][s]);
    }
    if (t < 64) {
        float S = (sred[0][t] + sred[1][t]) + (sred[2][t] + sred[3][t]);
        float Q = (qred[0][t] + qred[1][t]) + (qred[2][t] + qred[3][t]);
        size_t o = (size_t)blockIdx.y * (BATCH * SS) + (size_t)b * SS + s0 + t;
        psum[o] = S;
        psq[o] = Q;
    }
}

// ------------- QKV GEMM: interleaved hi/lo bf16 MFMA, LN folded epilogue -------------
// LN stats finalized inline from psum/psq partials (finalize_stats kernel removed).
// qkvint[b][o][s] = pack(rstd[s]*(sum_c wg[o][c]*x[c][s] - mean[s]*wsum[o]))
__global__ __launch_bounds__(256, 4) void qkv_mfma(
    const uint32* __restrict__ wgint, const uint32* __restrict__ xTint,
    const float* __restrict__ wsum, const float* __restrict__ psum,
    const float* __restrict__ psq, uint32* __restrict__ qkvint) {
    int b = blockIdx.z;
    int m0 = blockIdx.y * 128;  // o
    int n0 = blockIdx.x * 64;   // s
    int t = threadIdx.x;
    int wv = t >> 6, lane = t & 63, l15 = lane & 15, quad = lane >> 4;
    int wm = wv * 32;
    const uint32* Ab = wgint + (size_t)(m0 + wm) * C_IN;
    const uint32* Bb = xTint + ((size_t)b * SS + n0) * C_IN;
    f4v acc[2][4];
#pragma unroll
    for (int mt = 0; mt < 2; ++mt)
#pragma unroll
        for (int nt = 0; nt < 4; ++nt) acc[mt][nt] = (f4v){0.f, 0.f, 0.f, 0.f};
    u4v af[2][2], bf[2][4];
    auto ldA = [&](int ch, u4v* A) {
#pragma unroll
        for (int mt = 0; mt < 2; ++mt)
            A[mt] = *(const u4v*)(Ab + (size_t)(mt * 16 + l15) * C_IN + ch * 16 + quad * 4);
    };
    auto ldB = [&](int ch, u4v* B) {
#pragma unroll
        for (int nt = 0; nt < 4; ++nt)
            B[nt] = *(const u4v*)(Bb + (size_t)(nt * 16 + l15) * C_IN + ch * 16 + quad * 4);
    };
    ldA(0, af[0]);
    ldB(0, bf[0]);
#pragma unroll 2
    for (int ch = 0; ch < 16; ++ch) {
        int cur = ch & 1, nxt = cur ^ 1;
        if (ch + 1 < 16) { ldA(ch + 1, af[nxt]); ldB(ch + 1, bf[nxt]); }
        u4v br[4];
#pragma unroll
        for (int nt = 0; nt < 4; ++nt) br[nt] = rot16v(bf[cur][nt]);
#pragma unroll
        for (int mt = 0; mt < 2; ++mt) {
            s8v a = __builtin_bit_cast(s8v, af[cur][mt]);
#pragma unroll
            for (int nt = 0; nt < 4; ++nt) {
                acc[mt][nt] = mm(a, __builtin_bit_cast(s8v, bf[cur][nt]), acc[mt][nt]);
                acc[mt][nt] = mm(a, __builtin_bit_cast(s8v, br[nt]), acc[mt][nt]);
            }
        }
    }
    const int NP = BATCH * SS;
    float mnv[4], rsv[4];
#pragma unroll
    for (int nt = 0; nt < 4; ++nt) {
        int p = b * SS + n0 + nt * 16 + l15;
        float S = (psum[p] + psum[NP + p]) + (psum[2 * NP + p] + psum[3 * NP + p]);
        float Q = (psq[p] + psq[NP + p]) + (psq[2 * NP + p] + psq[3 * NP + p]);
        float mu = S * (1.0f / C_IN);
        mnv[nt] = mu;
        rsv[nt] = rsqrtf(Q * (1.0f / C_IN) - mu * mu + EPSV);
    }
#pragma unroll
    for (int mt = 0; mt < 2; ++mt)
#pragma unroll
        for (int r = 0; r < 4; ++r) {
            int m = m0 + wm + mt * 16 + quad * 4 + r;
            float ws = wsum[m];
            uint32* dst = qkvint + ((size_t)b * QKV3 + m) * SS + n0 + l15;
#pragma unroll
            for (int nt = 0; nt < 4; ++nt)
                dst[nt * 16] = pk_rnd(rsv[nt] * (acc[mt][nt][r] - mnv[nt] * ws));
        }
}

// ------- dwconv 3x3 + RoPE + hi/lo bf16 split.  Input qkvint packed u32.
// Q,K: [bh][s][d] (hi,lo separate); V: [bh][d][s] u32 = hi | lo<<16 -------
__global__ __launch_bounds__(256) void conv_rope(
    const uint32* __restrict__ qkvint, const float* __restrict__ dwq,
    const float* __restrict__ dwk, const float* __restrict__ dwv,
    const float* __restrict__ cosT, const float* __restrict__ sinT,
    unsigned short* __restrict__ qhi, unsigned short* __restrict__ qlo,
    unsigned short* __restrict__ khi, unsigned short* __restrict__ klo,
    uint32* __restrict__ vtint) {
    __shared__ float tile[64][65];
    int b = blockIdx.z;
    int part = blockIdx.y >> 3;
    int h = blockIdx.y & 7;
    int s0 = blockIdx.x * 64;
    int t = threadIdx.x;
    int sl = t & 63, dgrp = t >> 6;
    int s = s0 + sl;
    int y = s / 48, xx = s - y * 48;
    int bh = b * HEADS + h;
    const float* dw = (part == 0) ? dwq : (part == 1) ? dwk : dwv;
#pragma unroll
    for (int i = 0; i < 16; ++i) {
        int d = dgrp * 16 + i;
        int cch = part * HID + h * DH + d;
        const uint32* src = qkvint + ((size_t)b * QKV3 + cch) * SS;
        const float* wp = dw + (h * DH + d) * 9;
        float acc = 0.f;
#pragma unroll
        for (int dy = -1; dy <= 1; ++dy) {
            int yy = y + dy;
            if (yy < 0 || yy >= 48) continue;
#pragma unroll
            for (int dx = -1; dx <= 1; ++dx) {
                int xv = xx + dx;
                if (xv < 0 || xv >= 48) continue;
                acc += wp[(dy + 1) * 3 + (dx + 1)] * unpk(src[yy * 48 + xv]);
            }
        }
        if (part == 2) {
            size_t o = ((size_t)bh * DH + d) * SS + s;
            vtint[o] = pk_rnd(acc);
        } else {
            tile[d][sl] = acc;
        }
    }
    if (part == 2) return;
    __syncthreads();
    int d2 = t & 63, srow = t >> 6;
    unsigned short* hiA = (part == 0) ? qhi : khi;
    unsigned short* loA = (part == 0) ? qlo : klo;
#pragma unroll
    for (int i = 0; i < 16; ++i) {
        int sp = srow + 4 * i;
        float v0 = tile[d2][sp];
        float vp = tile[d2 ^ 32][sp];
        int f = d2 & 31;
        float cv = cosT[(s0 + sp) * 32 + f];
        float sv = sinT[(s0 + sp) * 32 + f];
        float rot = (d2 < 32) ? -vp : vp;
        float val = v0 * cv + rot * sv;
        if (part == 0) val *= SCALEV_LOG2E;  // scale * log2(e): attn uses 2^x
        size_t o = ((size_t)bh * SS + s0 + sp) * DH + d2;
        unsigned short hu = f2bf(val);
        hiA[o] = hu;
        loA[o] = f2bf(val - bf2f(hu));
    }
}

// -------- attention: key-split waves (16-key strip/wave, 64q x 16k).
// The 3-wave/SIMD campaign, composed from individually-verified pieces:
//  * R23/R10: Q tile in LDS (removes the 64-VGPR qf duplication; +3.8us win, correct)
//  * R22: K single-buffer with ldK(s+1) placed AFTER the QK cluster (correct; its
//    12us WAR cost at 2 waves should be absorbed by 3-wave TLP)
//  * R21/R8: __launch_bounds__(256,3) caps VGPR at 84 — R8 spilled because qf[4][4]
//    (64 regs) was still in the live set (~96 persistent). Now: kc 16 + vc 16 +
//    lsum 4 + addrs ~13 + sv 4 ~= 53 persistent, ~75 peak < 84 => fits.
// Occupancy: 3 blocks/CU (LDS 35.3KB allows 4), 1152 blocks = 1.5 rounds of 768.
// Sentinels: WRITE_SIZE must stay 18432 KB (spill detector); success = VGPR<=84,
// Occupancy ~27%+. Failure A (spill): revert to R10. Failure B (WAR-bound null):
// attn 190-215 at 28% occupancy.
__global__ __launch_bounds__(256, 3) void attn_mfma(
    const unsigned short* __restrict__ qhi, const unsigned short* __restrict__ qlo,
    const unsigned short* __restrict__ khi, const unsigned short* __restrict__ klo,
    const uint32* __restrict__ vtint, uint32* __restrict__ OTint) {
    __shared__ float lds[2][64][67];  // main loop: first 16KB = Q planes; epilogue: O-acc
    __shared__ float lsl[4][64];
    int n = blockIdx.y * 36 + blockIdx.x;   // 0..1151
    int xcd = n & 7, slot = n >> 3;         // slot 0..143
    int bh = (xcd << 2) | (slot / 36);      // 4 bh per XCD
    int i0 = (slot % 36) * 64;
    int t = threadIdx.x;
    int wv = t >> 6;
    int lane = t & 63;
    int l15 = lane & 15;
    int quad = lane >> 4;

    // ---- stage Q (hi+lo) into LDS: chunk (p,o,q) -> 8 bf16 at p*8192+o*1024+q*16.
    // Global reads fully coalesced (o fastest); one-time cost.
    {
        char* qw = (char*)lds;
#pragma unroll
        for (int r = 0; r < 4; ++r) {
            int idx = r * 256 + t;  // 1024 chunks: 2 planes x 8 octets x 64 queries
            int o = idx & 7;
            int q = (idx >> 3) & 63;
            int p = idx >> 9;
            const unsigned short* src =
                (p ? qlo : qhi) + ((size_t)bh * SS + i0 + q) * DH + o * 8;
            *(s8v*)(qw + p * 8192 + o * 1024 + q * 16) = *(const s8v*)src;
        }
    }
    __syncthreads();
    const char* qrd = (const char*)lds;
    const int qoff = l15 * 16 + quad * 1024;  // + imm: p*8192 + (j&1)*4096 + ig*256

    f4v oacc[4][4];
#pragma unroll
    for (int dt = 0; dt < 4; ++dt)
#pragma unroll
        for (int ig = 0; ig < 4; ++ig) oacc[dt][ig] = (f4v){0.f, 0.f, 0.f, 0.f};
    float lsum[4] = {0.f, 0.f, 0.f, 0.f};

    const size_t kbh = (size_t)bh * SS * DH;
    const uint32* vbase = vtint + (size_t)bh * DH * SS;
    const int jbase = wv * 16;  // wave's strip base; + s*64 per step

    s8v kc[4], vc[4];
    auto ldK = [&](int s, s8v* K) {
        size_t row = kbh + (size_t)(jbase + s * 64 + l15) * DH + quad * 8;
        K[0] = *(const s8v*)(khi + row);
        K[1] = *(const s8v*)(khi + row + 32);
        K[2] = *(const s8v*)(klo + row);
        K[3] = *(const s8v*)(klo + row + 32);
    };
    auto ldV = [&](int s, s8v* V) {
        size_t col = (size_t)(jbase + s * 64 + quad * 4);
#pragma unroll
        for (int dt = 0; dt < 4; ++dt)
            V[dt] = __builtin_bit_cast(
                s8v, *(const u4v*)(vbase + (size_t)(dt * 16 + l15) * SS + col));
    };
    ldK(0, kc);
#pragma unroll 2
    for (int s = 0; s < 36; ++s) {
        ldV(s, vc);  // issued at step top; QK below covers its latency
        // ---- S^T strip = K_strip . Q^T (Q frags from LDS) ----
        f4v sv[4];
#pragma unroll
        for (int ig = 0; ig < 4; ++ig) {
            s8v q0 = *(const s8v*)(qrd + (qoff + ig * 256));
            s8v q1 = *(const s8v*)(qrd + (qoff + ig * 256 + 4096));
            s8v q2 = *(const s8v*)(qrd + (qoff + ig * 256 + 8192));
            s8v q3 = *(const s8v*)(qrd + (qoff + ig * 256 + 12288));
            f4v sx = {0.f, 0.f, 0.f, 0.f};
            sx = mm(kc[0], q0, sx);
            sx = mm(kc[1], q1, sx);
            sx = mm(kc[0], q2, sx);
            sx = mm(kc[1], q3, sx);
            sx = mm(kc[2], q0, sx);
            sx = mm(kc[3], q1, sx);
            sv[ig] = sx;
        }
        // K for next step: WAR on kc pins this after the QK cluster; softmax+PV
        // below covers its latency. Single buffer => -16 VGPR (R22 pattern).
        if (s + 1 < 36) ldK(s + 1, kc);
        // ---- per-ig: p = 2^s, pack B1={ph|pl} B2={pl|ph}, then its PV MFMAs ----
        // mm(A,B1) = vh.ph + vl.pl ; mm(A,B2) = vh.pl + vl.ph  => exact product
#pragma unroll
        for (int ig = 0; ig < 4; ++ig) {
            float p0 = __builtin_amdgcn_exp2f(sv[ig][0]);
            float p1 = __builtin_amdgcn_exp2f(sv[ig][1]);
            float p2 = __builtin_amdgcn_exp2f(sv[ig][2]);
            float p3 = __builtin_amdgcn_exp2f(sv[ig][3]);
            lsum[ig] += (p0 + p1) + (p2 + p3);
            uint32 u0 = pk_trunc(p0), u1 = pk_trunc(p1);
            uint32 u2 = pk_trunc(p2), u3 = pk_trunc(p3);
            s8v B1 = pk4(u0, u1, u2, u3);
            s8v B2 = pk4(rot16(u0), rot16(u1), rot16(u2), rot16(u3));
#pragma unroll
            for (int dt = 0; dt < 4; ++dt) {
                oacc[dt][ig] = mm(vc[dt], B1, oacc[dt][ig]);
                oacc[dt][ig] = mm(vc[dt], B2, oacc[dt][ig]);
            }
        }
    }
    // ---- l: reduce over quads (keys) in-wave; cross-wave via LDS ----
#pragma unroll
    for (int ig = 0; ig < 4; ++ig) {
        float v = lsum[ig];
        v += __shfl_xor(v, 16);
        v += __shfl_xor(v, 32);
        if (quad == 0) lsl[wv][ig * 16 + l15] = v;
    }
    // All waves must be done READING the Q region before epilogue overwrites it.
    __syncthreads();
    // ---- phased epilogue: waves 0,1 write slots; waves 2,3 accumulate in-place ----
    if (wv < 2) {
#pragma unroll
        for (int dt = 0; dt < 4; ++dt)
#pragma unroll
            for (int ig = 0; ig < 4; ++ig)
#pragma unroll
                for (int r = 0; r < 4; ++r)
                    lds[wv][dt * 16 + quad * 4 + r][ig * 16 + l15] = oacc[dt][ig][r];
    }
    __syncthreads();
    if (wv >= 2) {
#pragma unroll
        for (int dt = 0; dt < 4; ++dt)
#pragma unroll
            for (int ig = 0; ig < 4; ++ig)
#pragma unroll
                for (int r = 0; r < 4; ++r)
                    lds[wv - 2][dt * 16 + quad * 4 + r][ig * 16 + l15] += oacc[dt][ig][r];
    }
    __syncthreads();
    // ---- normalize + pack + write OTint[b][s][h*64+d] (full l known: no combine) ----
    int q = t >> 2, dg = t & 3;
    float linv = 1.f / ((lsl[0][q] + lsl[1][q]) + (lsl[2][q] + lsl[3][q]));
    int b = bh >> 3, h = bh & 7;
    uint32* dst = OTint + ((size_t)b * SS + i0 + q) * HID + h * DH + dg * 16;
    u4v ov[4];
#pragma unroll
    for (int j4 = 0; j4 < 4; ++j4)
#pragma unroll
        for (int i = 0; i < 4; ++i) {
            int d = dg * 16 + j4 * 4 + i;
            ov[j4][i] = pk_rnd((lds[0][d][q] + lds[1][d][q]) * linv);
        }
#pragma unroll
    for (int j4 = 0; j4 < 4; ++j4) *(u4v*)(dst + j4 * 4) = ov[j4];
}

// ------------- output projection: interleaved hi/lo bf16 MFMA + bias -------------
__global__ __launch_bounds__(256, 4) void outproj_mfma(
    const uint32* __restrict__ OTint, const uint32* __restrict__ woutint,
    const float* __restrict__ b_out, float* __restrict__ out) {
    int b = blockIdx.z;
    int m0 = blockIdx.y * 32;   // o
    int n0 = blockIdx.x * 128;  // s
    int t = threadIdx.x;
    int wv = t >> 6, lane = t & 63, l15 = lane & 15, quad = lane >> 4;
    int wn = wv * 32;
    const uint32* Ab = woutint + (size_t)m0 * HID;
    const uint32* Bb = OTint + ((size_t)b * SS + n0 + wn) * HID;
    f4v acc[2][2];
#pragma unroll
    for (int mt = 0; mt < 2; ++mt)
#pragma unroll
        for (int nt = 0; nt < 2; ++nt) acc[mt][nt] = (f4v){0.f, 0.f, 0.f, 0.f};
    u4v af[2][2], bf[2][2];
    auto ldA = [&](int ch, u4v* A) {
#pragma unroll
        for (int mt = 0; mt < 2; ++mt)
            A[mt] = *(const u4v*)(Ab + (size_t)(mt * 16 + l15) * HID + ch * 16 + quad * 4);
    };
    auto ldB = [&](int ch, u4v* B) {
#pragma unroll
        for (int nt = 0; nt < 2; ++nt)
            B[nt] = *(const u4v*)(Bb + (size_t)(nt * 16 + l15) * HID + ch * 16 + quad * 4);
    };
    ldA(0, af[0]);
    ldB(0, bf[0]);
#pragma unroll 2
    for (int ch = 0; ch < 32; ++ch) {
        int cur = ch & 1, nxt = cur ^ 1;
        if (ch + 1 < 32) { ldA(ch + 1, af[nxt]); ldB(ch + 1, bf[nxt]); }
        u4v br[2];
#pragma unroll
        for (int nt = 0; nt < 2; ++nt) br[nt] = rot16v(bf[cur][nt]);
#pragma unroll
        for (int mt = 0; mt < 2; ++mt) {
            s8v a = __builtin_bit_cast(s8v, af[cur][mt]);
#pragma unroll
            for (int nt = 0; nt < 2; ++nt) {
                acc[mt][nt] = mm(a, __builtin_bit_cast(s8v, bf[cur][nt]), acc[mt][nt]);
                acc[mt][nt] = mm(a, __builtin_bit_cast(s8v, br[nt]), acc[mt][nt]);
            }
        }
    }
#pragma unroll
    for (int mt = 0; mt < 2; ++mt)
#pragma unroll
        for (int r = 0; r < 4; ++r) {
            int o = m0 + mt * 16 + quad * 4 + r;
            float bo = b_out[o];
            float* dst = out + ((size_t)b * C_IN + o) * SS + n0 + wn + l15;
#pragma unroll
            for (int nt = 0; nt < 2; ++nt) dst[nt * 16] = acc[mt][nt][r] + bo;
        }
}

extern "C" void kernel_launch(void* const* d_in, const int* in_sizes, int n_in,
                              void* d_out, int out_size, void* d_ws, size_t ws_size,
                              hipStream_t stream) {
    (void)in_sizes; (void)n_in; (void)out_size; (void)ws_size;
    const float* x     = (const float*)d_in[0];
    const float* g     = (const float*)d_in[1];
    const float* w_qkv = (const float*)d_in[2];
    const float* dwq   = (const float*)d_in[3];
    const float* dwk   = (const float*)d_in[4];
    const float* dwv   = (const float*)d_in[5];
    const float* w_out = (const float*)d_in[6];
    const float* b_out = (const float*)d_in[7];
    float* out = (float*)d_out;

    char* ws = (char*)d_ws;
    size_t off = 0;
    auto alloc = [&](size_t nbytes) -> void* {
        char* p = ws + off;
        off = (off + nbytes + 255) & ~(size_t)255;
        return (void*)p;
    };
    const size_t NSD = (size_t)BATCH * HEADS * SS * DH;  // 4.7M elements
    uint32* wgint   = (uint32*)alloc((size_t)QKV3 * C_IN * 4);
    uint32* woutint = (uint32*)alloc((size_t)C_IN * HID * 4);
    float* wsum = (float*)alloc((size_t)QKV3 * 4);
    float* psum = (float*)alloc((size_t)4 * BATCH * SS * 4);
    float* psq  = (float*)alloc((size_t)4 * BATCH * SS * 4);
    float* cosT = (float*)alloc((size_t)SS * 32 * 4);
    float* sinT = (float*)alloc((size_t)SS * 32 * 4);
    // scratchA: qkvint = BATCH*QKV3*SS u32 = 3*NSD u32 = 56.6 MB.
    // OTint (NSD u32) aliases its start — qkvint dead after conv_rope.
    char* scratchA = (char*)alloc((size_t)3 * NSD * 4);
    unsigned short* qhi  = (unsigned short*)alloc(NSD * 2);
    unsigned short* qlo  = (unsigned short*)alloc(NSD * 2);
    unsigned short* khi  = (unsigned short*)alloc(NSD * 2);
    unsigned short* klo  = (unsigned short*)alloc(NSD * 2);
    uint32* vtint = (uint32*)alloc(NSD * 4);
    // aliases (time-disjoint):
    uint32* xTint  = (uint32*)qhi;      // dead before conv_rope writes qhi
    uint32* qkvint = (uint32*)scratchA; // dead after conv_rope
    uint32* OTint  = (uint32*)scratchA;

    prep_all<<<QKV3 + 512 + 288, 256, 0, stream>>>(w_qkv, g, wgint, wsum,
                                                   w_out, woutint, cosT, sinT);
    xt_pack<<<dim3(36, 4, BATCH), 256, 0, stream>>>(x, xTint, psum, psq);
    qkv_mfma<<<dim3(36, 12, BATCH), 256, 0, stream>>>(wgint, xTint, wsum, psum, psq,
                                                      qkvint);
    conv_rope<<<dim3(36, 24, BATCH), 256, 0, stream>>>(qkvint, dwq, dwk, dwv, cosT, sinT,
                                                       qhi, qlo, khi, klo, vtint);
    attn_mfma<<<dim3(36, 32), 256, 0, stream>>>(qhi, qlo, khi, klo, vtint, OTint);
    outproj_mfma<<<dim3(18, 8, BATCH), 256, 0, stream>>>(OTint, woutint, b_out, out);
}

// Round 12
// 471.841 us; speedup vs baseline: 1.6831x; 1.6831x over previous
//
#include <hip/hip_runtime.h>
#include <math.h>

#define SS 2304
#define C_IN 256
#define HID 512
#define QKV3 1536
#define HEADS 8
#define DH 64
#define BATCH 4
#define EPSV 1e-5f
// SCALE folded with log2(e): softmax_j 2^(s_j*log2e) == softmax_j e^(s_j),
// so attention uses v_exp_f32 (2^x) directly with no per-p multiply.
#define SCALEV_LOG2E 0.18033688011112042f

typedef short s8v __attribute__((ext_vector_type(8)));
typedef float f4v __attribute__((ext_vector_type(4)));
typedef unsigned int u4v __attribute__((ext_vector_type(4)));
typedef unsigned int uint32;

static __device__ inline unsigned short f2bf(float x) {
    unsigned int u = __float_as_uint(x);
    u += 0x7fffu + ((u >> 16) & 1u);
    return (unsigned short)(u >> 16);
}
static __device__ inline float bf2f(unsigned short h) {
    return __uint_as_float((unsigned int)h << 16);
}
static __device__ inline f4v mm(s8v a, s8v b, f4v c) {
    return __builtin_amdgcn_mfma_f32_16x16x32_bf16(a, b, c, 0, 0, 0);
}
static __device__ inline s8v pk4(uint32 a, uint32 b, uint32 c, uint32 d) {
    u4v t; t[0] = a; t[1] = b; t[2] = c; t[3] = d;
    return __builtin_bit_cast(s8v, t);
}
// ---- hi/lo bf16 pack helpers (R19 v_perm final-assembly; operand-order safe:
// consumers symmetric under 16-bit rotation).  hi=rnd-nearest, lo=trunc residual.
static __device__ inline uint32 pk_rnd(float x) {
    unsigned int u = __float_as_uint(x);
    unsigned int uh = (u + (0x7fffu + ((u >> 16) & 1u))) & 0xffff0000u;
    float r = x - __uint_as_float(uh);
#if __has_builtin(__builtin_amdgcn_perm)
    return __builtin_amdgcn_perm(__float_as_uint(r), uh, 0x07060302u);
#else
    return (uh >> 16) | (__float_as_uint(r) & 0xffff0000u);
#endif
}
// trunc/trunc variant (cheap, hot attention path; softmax cancels the bias)
static __device__ inline uint32 pk_trunc(float x) {
    unsigned int u = __float_as_uint(x);
    unsigned int h = u & 0xffff0000u;
    float r = x - __uint_as_float(h);
#if __has_builtin(__builtin_amdgcn_perm)
    return __builtin_amdgcn_perm(__float_as_uint(r), u, 0x07060302u);
#else
    return (h >> 16) | (__float_as_uint(r) & 0xffff0000u);
#endif
}
// unpack {hi|lo} u32 back to ~fp32 (half-order agnostic: sums both halves)
static __device__ inline float unpk(uint32 u) {
    return __uint_as_float(u << 16) + __uint_as_float(u & 0xffff0000u);
}
static __device__ inline uint32 rot16(uint32 u) { return (u >> 16) | (u << 16); }
static __device__ inline u4v rot16v(u4v u) {
    u4v r; r[0] = rot16(u[0]); r[1] = rot16(u[1]); r[2] = rot16(u[2]); r[3] = rot16(u[3]);
    return r;
}

// ---- merged prep: [0,1536) wgint+wsum | [1536,2048) woutint | [2048,2336) rope ----
__global__ void prep_all(const float* __restrict__ w_qkv, const float* __restrict__ g,
                         uint32* __restrict__ wgint, float* __restrict__ wsum,
                         const float* __restrict__ w_out, uint32* __restrict__ woutint,
                         float* __restrict__ cosT, float* __restrict__ sinT) {
    __shared__ float red[256];
    int bid = blockIdx.x;
    int t = threadIdx.x;
    if (bid < QKV3) {
        int o = bid, c = t;
        float v = w_qkv[o * C_IN + c] * g[c];
        wgint[o * C_IN + c] = pk_rnd(v);
        red[c] = v;
        __syncthreads();
        for (int st = 128; st > 0; st >>= 1) {
            if (c < st) red[c] += red[c + st];
            __syncthreads();
        }
        if (c == 0) wsum[o] = red[0];
    } else if (bid < QKV3 + 512) {
        int idx = (bid - QKV3) * 256 + t;  // 131072 total
        woutint[idx] = pk_rnd(w_out[idx]);
    } else {
        int idx = (bid - QKV3 - 512) * 256 + t;  // 73728 total
        int s = idx >> 5, f = idx & 31;
        double inv = pow(10000.0, -(double)f / 32.0);
        double ang = (double)s * inv;
        cosT[idx] = (float)cos(ang);
        sinT[idx] = (float)sin(ang);
    }
}

// ------ transpose + pack x -> xTint[b][s][c] u32, and per-c-chunk LN partials ------
__global__ __launch_bounds__(256) void xt_pack(const float* __restrict__ x,
                                               uint32* __restrict__ xTint,
                                               float* __restrict__ psum,
                                               float* __restrict__ psq) {
    __shared__ float tile[64][65];
    __shared__ float sred[4][64];
    __shared__ float qred[4][64];
    int b = blockIdx.z;
    int c0 = blockIdx.y * 64;
    int s0 = blockIdx.x * 64;
    int t = threadIdx.x;
    int sl = t & 63, cg = t >> 6;
    float ps = 0.f, pq = 0.f;
#pragma unroll
    for (int i = 0; i < 16; ++i) {
        int c = cg * 16 + i;
        float v = x[((size_t)b * C_IN + c0 + c) * SS + s0 + sl];
        tile[c][sl] = v;
        ps += v;
        pq += v * v;
    }
    sred[cg][sl] = ps;
    qred[cg][sl] = pq;
    __syncthreads();
    int cl = t & 63, sg = t >> 6;
#pragma unroll
    for (int i = 0; i < 16; ++i) {
        int s = sg * 16 + i;
        xTint[((size_t)b * SS + s0 + s) * C_IN + c0 + cl] = pk_rnd(tile[cl][s]);
    }
    if (t < 64) {
        float S = (sred[0][t] + sred[1][t]) + (sred[2][t] + sred[3][t]);
        float Q = (qred[0][t] + qred[1][t]) + (qred[2][t] + qred[3][t]);
        size_t o = (size_t)blockIdx.y * (BATCH * SS) + (size_t)b * SS + s0 + t;
        psum[o] = S;
        psq[o] = Q;
    }
}

// ------------- QKV GEMM: interleaved hi/lo bf16 MFMA, LN folded epilogue -------------
// LN stats finalized inline from psum/psq partials (finalize_stats kernel removed).
// qkvint[b][o][s] = pack(rstd[s]*(sum_c wg[o][c]*x[c][s] - mean[s]*wsum[o]))
__global__ __launch_bounds__(256, 4) void qkv_mfma(
    const uint32* __restrict__ wgint, const uint32* __restrict__ xTint,
    const float* __restrict__ wsum, const float* __restrict__ psum,
    const float* __restrict__ psq, uint32* __restrict__ qkvint) {
    int b = blockIdx.z;
    int m0 = blockIdx.y * 128;  // o
    int n0 = blockIdx.x * 64;   // s
    int t = threadIdx.x;
    int wv = t >> 6, lane = t & 63, l15 = lane & 15, quad = lane >> 4;
    int wm = wv * 32;
    const uint32* Ab = wgint + (size_t)(m0 + wm) * C_IN;
    const uint32* Bb = xTint + ((size_t)b * SS + n0) * C_IN;
    f4v acc[2][4];
#pragma unroll
    for (int mt = 0; mt < 2; ++mt)
#pragma unroll
        for (int nt = 0; nt < 4; ++nt) acc[mt][nt] = (f4v){0.f, 0.f, 0.f, 0.f};
    u4v af[2][2], bf[2][4];
    auto ldA = [&](int ch, u4v* A) {
#pragma unroll
        for (int mt = 0; mt < 2; ++mt)
            A[mt] = *(const u4v*)(Ab + (size_t)(mt * 16 + l15) * C_IN + ch * 16 + quad * 4);
    };
    auto ldB = [&](int ch, u4v* B) {
#pragma unroll
        for (int nt = 0; nt < 4; ++nt)
            B[nt] = *(const u4v*)(Bb + (size_t)(nt * 16 + l15) * C_IN + ch * 16 + quad * 4);
    };
    ldA(0, af[0]);
    ldB(0, bf[0]);
#pragma unroll 2
    for (int ch = 0; ch < 16; ++ch) {
        int cur = ch & 1, nxt = cur ^ 1;
        if (ch + 1 < 16) { ldA(ch + 1, af[nxt]); ldB(ch + 1, bf[nxt]); }
        u4v br[4];
#pragma unroll
        for (int nt = 0; nt < 4; ++nt) br[nt] = rot16v(bf[cur][nt]);
#pragma unroll
        for (int mt = 0; mt < 2; ++mt) {
            s8v a = __builtin_bit_cast(s8v, af[cur][mt]);
#pragma unroll
            for (int nt = 0; nt < 4; ++nt) {
                acc[mt][nt] = mm(a, __builtin_bit_cast(s8v, bf[cur][nt]), acc[mt][nt]);
                acc[mt][nt] = mm(a, __builtin_bit_cast(s8v, br[nt]), acc[mt][nt]);
            }
        }
    }
    const int NP = BATCH * SS;
    float mnv[4], rsv[4];
#pragma unroll
    for (int nt = 0; nt < 4; ++nt) {
        int p = b * SS + n0 + nt * 16 + l15;
        float S = (psum[p] + psum[NP + p]) + (psum[2 * NP + p] + psum[3 * NP + p]);
        float Q = (psq[p] + psq[NP + p]) + (psq[2 * NP + p] + psq[3 * NP + p]);
        float mu = S * (1.0f / C_IN);
        mnv[nt] = mu;
        rsv[nt] = rsqrtf(Q * (1.0f / C_IN) - mu * mu + EPSV);
    }
#pragma unroll
    for (int mt = 0; mt < 2; ++mt)
#pragma unroll
        for (int r = 0; r < 4; ++r) {
            int m = m0 + wm + mt * 16 + quad * 4 + r;
            float ws = wsum[m];
            uint32* dst = qkvint + ((size_t)b * QKV3 + m) * SS + n0 + l15;
#pragma unroll
            for (int nt = 0; nt < 4; ++nt)
                dst[nt * 16] = pk_rnd(rsv[nt] * (acc[mt][nt][r] - mnv[nt] * ws));
        }
}

// ------- dwconv 3x3 + RoPE + hi/lo bf16 split.  Input qkvint packed u32.
// Q,K: [bh][s][d] (hi,lo separate); V: [bh][d][s] u32 = hi | lo<<16 -------
__global__ __launch_bounds__(256) void conv_rope(
    const uint32* __restrict__ qkvint, const float* __restrict__ dwq,
    const float* __restrict__ dwk, const float* __restrict__ dwv,
    const float* __restrict__ cosT, const float* __restrict__ sinT,
    unsigned short* __restrict__ qhi, unsigned short* __restrict__ qlo,
    unsigned short* __restrict__ khi, unsigned short* __restrict__ klo,
    uint32* __restrict__ vtint) {
    __shared__ float tile[64][65];
    int b = blockIdx.z;
    int part = blockIdx.y >> 3;
    int h = blockIdx.y & 7;
    int s0 = blockIdx.x * 64;
    int t = threadIdx.x;
    int sl = t & 63, dgrp = t >> 6;
    int s = s0 + sl;
    int y = s / 48, xx = s - y * 48;
    int bh = b * HEADS + h;
    const float* dw = (part == 0) ? dwq : (part == 1) ? dwk : dwv;
#pragma unroll
    for (int i = 0; i < 16; ++i) {
        int d = dgrp * 16 + i;
        int cch = part * HID + h * DH + d;
        const uint32* src = qkvint + ((size_t)b * QKV3 + cch) * SS;
        const float* wp = dw + (h * DH + d) * 9;
        float acc = 0.f;
#pragma unroll
        for (int dy = -1; dy <= 1; ++dy) {
            int yy = y + dy;
            if (yy < 0 || yy >= 48) continue;
#pragma unroll
            for (int dx = -1; dx <= 1; ++dx) {
                int xv = xx + dx;
                if (xv < 0 || xv >= 48) continue;
                acc += wp[(dy + 1) * 3 + (dx + 1)] * unpk(src[yy * 48 + xv]);
            }
        }
        if (part == 2) {
            size_t o = ((size_t)bh * DH + d) * SS + s;
            vtint[o] = pk_rnd(acc);
        } else {
            tile[d][sl] = acc;
        }
    }
    if (part == 2) return;
    __syncthreads();
    int d2 = t & 63, srow = t >> 6;
    unsigned short* hiA = (part == 0) ? qhi : khi;
    unsigned short* loA = (part == 0) ? qlo : klo;
#pragma unroll
    for (int i = 0; i < 16; ++i) {
        int sp = srow + 4 * i;
        float v0 = tile[d2][sp];
        float vp = tile[d2 ^ 32][sp];
        int f = d2 & 31;
        float cv = cosT[(s0 + sp) * 32 + f];
        float sv = sinT[(s0 + sp) * 32 + f];
        float rot = (d2 < 32) ? -vp : vp;
        float val = v0 * cv + rot * sv;
        if (part == 0) val *= SCALEV_LOG2E;  // scale * log2(e): attn uses 2^x
        size_t o = ((size_t)bh * SS + s0 + sp) * DH + d2;
        unsigned short hu = f2bf(val);
        hiA[o] = hu;
        loA[o] = f2bf(val - bf2f(hu));
    }
}

// -------- attention: key-split waves (16-key strip/wave, 64q x 16k).  FINAL (R10).
// Session verdicts, each measured on hardware:
//  * setprio: null (R18); VALU diet: mechanical win, dur flat (R19) => not VALU-bound
//  * Q-tile 48: +33% K/V traffic => load-bound regression (R16). 64 is right.
//  * K single-buffer at 2 waves: WAR serialization, -12us (R22 pattern, R9 bench)
//  * 3-wave campaign: cap(256,3)=84 VGPR < ~96-100 peak live set => spilled in all
//    three forms (R8, R11); unforced allocator parks at 116-124 VGPR (R9, R10)
//  * Q-in-LDS (this config): -4us, VGPR 120, no spill — best known.
// Structure: Q tile in LDS (aliases epilogue buffer, barrier-protected), K double-
// buffered in regs, V single-buffered, fused per-ig softmax->PV, exp2-folded scale,
// v_perm packs, stride-67 epilogue, XCD-aware block swizzle. attn ~198us.
__global__ __launch_bounds__(256, 2) void attn_mfma(
    const unsigned short* __restrict__ qhi, const unsigned short* __restrict__ qlo,
    const unsigned short* __restrict__ khi, const unsigned short* __restrict__ klo,
    const uint32* __restrict__ vtint, uint32* __restrict__ OTint) {
    __shared__ float lds[2][64][67];  // main loop: first 16KB = Q planes; epilogue: O-acc
    __shared__ float lsl[4][64];
    int n = blockIdx.y * 36 + blockIdx.x;   // 0..1151
    int xcd = n & 7, slot = n >> 3;         // slot 0..143
    int bh = (xcd << 2) | (slot / 36);      // 4 bh per XCD
    int i0 = (slot % 36) * 64;
    int t = threadIdx.x;
    int wv = t >> 6;
    int lane = t & 63;
    int l15 = lane & 15;
    int quad = lane >> 4;

    // ---- stage Q (hi+lo) into LDS: chunk (p,o,q) -> 8 bf16 at p*8192+o*1024+q*16.
    // Global reads fully coalesced (o fastest); one-time cost.
    {
        char* qw = (char*)lds;
#pragma unroll
        for (int r = 0; r < 4; ++r) {
            int idx = r * 256 + t;  // 1024 chunks: 2 planes x 8 octets x 64 queries
            int o = idx & 7;
            int q = (idx >> 3) & 63;
            int p = idx >> 9;
            const unsigned short* src =
                (p ? qlo : qhi) + ((size_t)bh * SS + i0 + q) * DH + o * 8;
            *(s8v*)(qw + p * 8192 + o * 1024 + q * 16) = *(const s8v*)src;
        }
    }
    __syncthreads();
    const char* qrd = (const char*)lds;
    const int qoff = l15 * 16 + quad * 1024;  // + imm: p*8192 + (j&1)*4096 + ig*256

    f4v oacc[4][4];
#pragma unroll
    for (int dt = 0; dt < 4; ++dt)
#pragma unroll
        for (int ig = 0; ig < 4; ++ig) oacc[dt][ig] = (f4v){0.f, 0.f, 0.f, 0.f};
    float lsum[4] = {0.f, 0.f, 0.f, 0.f};

    const size_t kbh = (size_t)bh * SS * DH;
    const uint32* vbase = vtint + (size_t)bh * DH * SS;
    const int jbase = wv * 16;  // wave's strip base; + s*64 per step

    s8v kc[2][4], vc[4];
    auto ldK = [&](int s, s8v* K) {
        size_t row = kbh + (size_t)(jbase + s * 64 + l15) * DH + quad * 8;
        K[0] = *(const s8v*)(khi + row);
        K[1] = *(const s8v*)(khi + row + 32);
        K[2] = *(const s8v*)(klo + row);
        K[3] = *(const s8v*)(klo + row + 32);
    };
    auto ldV = [&](int s, s8v* V) {
        size_t col = (size_t)(jbase + s * 64 + quad * 4);
#pragma unroll
        for (int dt = 0; dt < 4; ++dt)
            V[dt] = __builtin_bit_cast(
                s8v, *(const u4v*)(vbase + (size_t)(dt * 16 + l15) * SS + col));
    };
    ldK(0, kc[0]);
#pragma unroll 2
    for (int s = 0; s < 36; ++s) {
        int cur = s & 1, nxt = cur ^ 1;
        ldV(s, vc);  // issued at step top; QK below covers its latency
        if (s + 1 < 36) { ldK(s + 1, kc[nxt]); }
        // ---- per-ig fully fused: Q-frags from LDS -> QK^T -> p=2^s -> pack -> PV ----
        // mm(A,B1) = vh.ph + vl.pl ; mm(A,B2) = vh.pl + vl.ph  => exact product
#pragma unroll
        for (int ig = 0; ig < 4; ++ig) {
            s8v q0 = *(const s8v*)(qrd + (qoff + ig * 256));
            s8v q1 = *(const s8v*)(qrd + (qoff + ig * 256 + 4096));
            s8v q2 = *(const s8v*)(qrd + (qoff + ig * 256 + 8192));
            s8v q3 = *(const s8v*)(qrd + (qoff + ig * 256 + 12288));
            f4v sx = {0.f, 0.f, 0.f, 0.f};
            sx = mm(kc[cur][0], q0, sx);
            sx = mm(kc[cur][1], q1, sx);
            sx = mm(kc[cur][0], q2, sx);
            sx = mm(kc[cur][1], q3, sx);
            sx = mm(kc[cur][2], q0, sx);
            sx = mm(kc[cur][3], q1, sx);
            float p0 = __builtin_amdgcn_exp2f(sx[0]);
            float p1 = __builtin_amdgcn_exp2f(sx[1]);
            float p2 = __builtin_amdgcn_exp2f(sx[2]);
            float p3 = __builtin_amdgcn_exp2f(sx[3]);
            lsum[ig] += (p0 + p1) + (p2 + p3);
            uint32 u0 = pk_trunc(p0), u1 = pk_trunc(p1);
            uint32 u2 = pk_trunc(p2), u3 = pk_trunc(p3);
            s8v B1 = pk4(u0, u1, u2, u3);
            s8v B2 = pk4(rot16(u0), rot16(u1), rot16(u2), rot16(u3));
#pragma unroll
            for (int dt = 0; dt < 4; ++dt) {
                oacc[dt][ig] = mm(vc[dt], B1, oacc[dt][ig]);
                oacc[dt][ig] = mm(vc[dt], B2, oacc[dt][ig]);
            }
        }
    }
    // ---- l: reduce over quads (keys) in-wave; cross-wave via LDS ----
#pragma unroll
    for (int ig = 0; ig < 4; ++ig) {
        float v = lsum[ig];
        v += __shfl_xor(v, 16);
        v += __shfl_xor(v, 32);
        if (quad == 0) lsl[wv][ig * 16 + l15] = v;
    }
    // All waves must be done READING the Q region before epilogue overwrites it.
    __syncthreads();
    // ---- phased epilogue: waves 0,1 write slots; waves 2,3 accumulate in-place ----
    if (wv < 2) {
#pragma unroll
        for (int dt = 0; dt < 4; ++dt)
#pragma unroll
            for (int ig = 0; ig < 4; ++ig)
#pragma unroll
                for (int r = 0; r < 4; ++r)
                    lds[wv][dt * 16 + quad * 4 + r][ig * 16 + l15] = oacc[dt][ig][r];
    }
    __syncthreads();
    if (wv >= 2) {
#pragma unroll
        for (int dt = 0; dt < 4; ++dt)
#pragma unroll
            for (int ig = 0; ig < 4; ++ig)
#pragma unroll
                for (int r = 0; r < 4; ++r)
                    lds[wv - 2][dt * 16 + quad * 4 + r][ig * 16 + l15] += oacc[dt][ig][r];
    }
    __syncthreads();
    // ---- normalize + pack + write OTint[b][s][h*64+d] (full l known: no combine) ----
    int q = t >> 2, dg = t & 3;
    float linv = 1.f / ((lsl[0][q] + lsl[1][q]) + (lsl[2][q] + lsl[3][q]));
    int b = bh >> 3, h = bh & 7;
    uint32* dst = OTint + ((size_t)b * SS + i0 + q) * HID + h * DH + dg * 16;
    u4v ov[4];
#pragma unroll
    for (int j4 = 0; j4 < 4; ++j4)
#pragma unroll
        for (int i = 0; i < 4; ++i) {
            int d = dg * 16 + j4 * 4 + i;
            ov[j4][i] = pk_rnd((lds[0][d][q] + lds[1][d][q]) * linv);
        }
#pragma unroll
    for (int j4 = 0; j4 < 4; ++j4) *(u4v*)(dst + j4 * 4) = ov[j4];
}

// ------------- output projection: interleaved hi/lo bf16 MFMA + bias -------------
__global__ __launch_bounds__(256, 4) void outproj_mfma(
    const uint32* __restrict__ OTint, const uint32* __restrict__ woutint,
    const float* __restrict__ b_out, float* __restrict__ out) {
    int b = blockIdx.z;
    int m0 = blockIdx.y * 32;   // o
    int n0 = blockIdx.x * 128;  // s
    int t = threadIdx.x;
    int wv = t >> 6, lane = t & 63, l15 = lane & 15, quad = lane >> 4;
    int wn = wv * 32;
    const uint32* Ab = woutint + (size_t)m0 * HID;
    const uint32* Bb = OTint + ((size_t)b * SS + n0 + wn) * HID;
    f4v acc[2][2];
#pragma unroll
    for (int mt = 0; mt < 2; ++mt)
#pragma unroll
        for (int nt = 0; nt < 2; ++nt) acc[mt][nt] = (f4v){0.f, 0.f, 0.f, 0.f};
    u4v af[2][2], bf[2][2];
    auto ldA = [&](int ch, u4v* A) {
#pragma unroll
        for (int mt = 0; mt < 2; ++mt)
            A[mt] = *(const u4v*)(Ab + (size_t)(mt * 16 + l15) * HID + ch * 16 + quad * 4);
    };
    auto ldB = [&](int ch, u4v* B) {
#pragma unroll
        for (int nt = 0; nt < 2; ++nt)
            B[nt] = *(const u4v*)(Bb + (size_t)(nt * 16 + l15) * HID + ch * 16 + quad * 4);
    };
    ldA(0, af[0]);
    ldB(0, bf[0]);
#pragma unroll 2
    for (int ch = 0; ch < 32; ++ch) {
        int cur = ch & 1, nxt = cur ^ 1;
        if (ch + 1 < 32) { ldA(ch + 1, af[nxt]); ldB(ch + 1, bf[nxt]); }
        u4v br[2];
#pragma unroll
        for (int nt = 0; nt < 2; ++nt) br[nt] = rot16v(bf[cur][nt]);
#pragma unroll
        for (int mt = 0; mt < 2; ++mt) {
            s8v a = __builtin_bit_cast(s8v, af[cur][mt]);
#pragma unroll
            for (int nt = 0; nt < 2; ++nt) {
                acc[mt][nt] = mm(a, __builtin_bit_cast(s8v, bf[cur][nt]), acc[mt][nt]);
                acc[mt][nt] = mm(a, __builtin_bit_cast(s8v, br[nt]), acc[mt][nt]);
            }
        }
    }
#pragma unroll
    for (int mt = 0; mt < 2; ++mt)
#pragma unroll
        for (int r = 0; r < 4; ++r) {
            int o = m0 + mt * 16 + quad * 4 + r;
            float bo = b_out[o];
            float* dst = out + ((size_t)b * C_IN + o) * SS + n0 + wn + l15;
#pragma unroll
            for (int nt = 0; nt < 2; ++nt) dst[nt * 16] = acc[mt][nt][r] + bo;
        }
}

extern "C" void kernel_launch(void* const* d_in, const int* in_sizes, int n_in,
                              void* d_out, int out_size, void* d_ws, size_t ws_size,
                              hipStream_t stream) {
    (void)in_sizes; (void)n_in; (void)out_size; (void)ws_size;
    const float* x     = (const float*)d_in[0];
    const float* g     = (const float*)d_in[1];
    const float* w_qkv = (const float*)d_in[2];
    const float* dwq   = (const float*)d_in[3];
    const float* dwk   = (const float*)d_in[4];
    const float* dwv   = (const float*)d_in[5];
    const float* w_out = (const float*)d_in[6];
    const float* b_out = (const float*)d_in[7];
    float* out = (float*)d_out;

    char* ws = (char*)d_ws;
    size_t off = 0;
    auto alloc = [&](size_t nbytes) -> void* {
        char* p = ws + off;
        off = (off + nbytes + 255) & ~(size_t)255;
        return (void*)p;
    };
    const size_t NSD = (size_t)BATCH * HEADS * SS * DH;  // 4.7M elements
    uint32* wgint   = (uint32*)alloc((size_t)QKV3 * C_IN * 4);
    uint32* woutint = (uint32*)alloc((size_t)C_IN * HID * 4);
    float* wsum = (float*)alloc((size_t)QKV3 * 4);
    float* psum = (float*)alloc((size_t)4 * BATCH * SS * 4);
    float* psq  = (float*)alloc((size_t)4 * BATCH * SS * 4);
    float* cosT = (float*)alloc((size_t)SS * 32 * 4);
    float* sinT = (float*)alloc((size_t)SS * 32 * 4);
    // scratchA: qkvint = BATCH*QKV3*SS u32 = 3*NSD u32 = 56.6 MB.
    // OTint (NSD u32) aliases its start — qkvint dead after conv_rope.
    char* scratchA = (char*)alloc((size_t)3 * NSD * 4);
    unsigned short* qhi  = (unsigned short*)alloc(NSD * 2);
    unsigned short* qlo  = (unsigned short*)alloc(NSD * 2);
    unsigned short* khi  = (unsigned short*)alloc(NSD * 2);
    unsigned short* klo  = (unsigned short*)alloc(NSD * 2);
    uint32* vtint = (uint32*)alloc(NSD * 4);
    // aliases (time-disjoint):
    uint32* xTint  = (uint32*)qhi;      // dead before conv_rope writes qhi
    uint32* qkvint = (uint32*)scratchA; // dead after conv_rope
    uint32* OTint  = (uint32*)scratchA;

    prep_all<<<QKV3 + 512 + 288, 256, 0, stream>>>(w_qkv, g, wgint, wsum,
                                                   w_out, woutint, cosT, sinT);
    xt_pack<<<dim3(36, 4, BATCH), 256, 0, stream>>>(x, xTint, psum, psq);
    qkv_mfma<<<dim3(36, 12, BATCH), 256, 0, stream>>>(wgint, xTint, wsum, psum, psq,
                                                      qkvint);
    conv_rope<<<dim3(36, 24, BATCH), 256, 0, stream>>>(qkvint, dwq, dwk, dwv, cosT, sinT,
                                                       qhi, qlo, khi, klo, vtint);
    attn_mfma<<<dim3(36, 32), 256, 0, stream>>>(qhi, qlo, khi, klo, vtint, OTint);
    outproj_mfma<<<dim3(18, 8, BATCH), 256, 0, stream>>>(OTint, woutint, b_out, out);
}